// Round 6
// baseline (153.161 us; speedup 1.0000x reference)
//
#include <hip/hip_runtime.h>
#include <stdint.h>

// Problem constants (fixed by setup_inputs): B=2, C=80, A=1024, H=W=2048
#define BATCH 2
#define NCLS 80
#define NP (BATCH * NCLS)   // 160 independent NMS problems
#define NA 1024
#define NWORD 16            // NA/64
#define NWBLK 128           // W blocks: 2 batches x 16 rowblocks x 4 word-quarters
#define IMG_W 2048.0f
#define IMG_H 2048.0f

// monotone float -> uint mapping (ascending uint order == ascending float order)
__device__ __forceinline__ unsigned enc_f32(float f) {
  unsigned u = __float_as_uint(f);
  return (u & 0x80000000u) ? ~u : (u | 0x80000000u);
}

// 64-bit cross-lane xor shuffle (two 32-bit halves; partner always in-wave)
__device__ __forceinline__ unsigned long long shflx64(unsigned long long v, int m) {
  int lo = __shfl_xor((int)(unsigned)v, m, 64);
  int hi = __shfl_xor((int)(unsigned)(v >> 32), m, 64);
  return ((unsigned long long)(unsigned)hi << 32) | (unsigned)lo;
}

__device__ __forceinline__ void cas64(unsigned long long& x, unsigned long long& y, bool up) {
  if ((x > y) == up) { unsigned long long t = x; x = y; y = t; }
}

// ---------------------------------------------------------------------------
// K1: per-batch symmetric W matrix ONLY. 128 blocks = 2 batches x 16 row
// blocks x 4 word-quarters; each wave computes 1 word (64 IOUs/thread).
// Same verified decode + IOU expressions (bit-identical).
// ---------------------------------------------------------------------------
__global__ __launch_bounds__(256) void wmat_kernel(
    const float* __restrict__ reg_pred,   // (B, 4, A)
    const float* __restrict__ anchors,    // (A, 4)
    unsigned long long* __restrict__ W)   // (B, NA, NWORD)
{
#pragma clang fp contract(off)
  const int tid  = threadIdx.x;
  const int wb   = blockIdx.x;         // 0..127
  const int b    = wb >> 6;            // batch
  const int sub  = wb & 63;
  const int rblk = sub >> 2;           // 0..15 row block of 64
  const int qq   = sub & 3;            // word quarter
  const int lane = tid & 63;
  const int wq   = tid >> 6;           // wave id 0..3

  __shared__ __align__(16) float4 sb[NA];   // 16 KB decoded boxes

  const float* regb = reg_pred + (size_t)b * 4 * NA;
  {
    // vectorized decode, e = tid*4+m (identical float expressions)
    float4 x4 = ((const float4*)(regb + 0 * NA))[tid];
    float4 y4 = ((const float4*)(regb + 1 * NA))[tid];
    float4 w4 = ((const float4*)(regb + 2 * NA))[tid];
    float4 h4 = ((const float4*)(regb + 3 * NA))[tid];
    float dxs[4] = {x4.x, x4.y, x4.z, x4.w};
    float dys[4] = {y4.x, y4.y, y4.z, y4.w};
    float dws[4] = {w4.x, w4.y, w4.z, w4.w};
    float dhs[4] = {h4.x, h4.y, h4.z, h4.w};
#pragma unroll
    for (int m = 0; m < 4; ++m) {
      const int a = tid * 4 + m;
      float4 an = ((const float4*)anchors)[a];
      float w  = an.z - an.x;
      float h  = an.w - an.y;
      float cx = an.x + 0.5f * w;
      float cy = an.y + 0.5f * h;
      float dx = dxs[m] * 0.1f;
      float dy = dys[m] * 0.1f;
      float dw = dws[m] * 0.2f;
      float dh = dhs[m] * 0.2f;
      float pcx = cx + dx * w;
      float pcy = cy + dy * h;
      float pw  = expf(dw) * w;
      float ph  = expf(dh) * h;
      float x1 = fmaxf(pcx - 0.5f * pw, 0.0f);
      float y1 = pcy - 0.5f * ph;
      x1 = fmaxf(x1, 0.0f);
      y1 = fmaxf(y1, 0.0f);
      float x2 = fminf(pcx + 0.5f * pw, IMG_W);
      float y2 = fminf(pcy + 0.5f * ph, IMG_H);
      sb[a] = make_float4(x1, y1, x2, y2);
    }
  }
  __syncthreads();

  const int r = rblk * 64 + lane;      // this lane's row
  float4 br = sb[r];
  float  ar = (br.z - br.x) * (br.w - br.y);

  const int kw = qq * 4 + wq;          // word index 0..15 (wave-uniform)
  const int jbase = kw * 64;
  unsigned long long bits = 0ull;
#pragma unroll 8
  for (int jj = 0; jj < 64; ++jj) {
    float4 bj = sb[jbase + jj];        // wave-broadcast b128
    float  aj = (bj.z - bj.x) * (bj.w - bj.y);
    float ix1 = fmaxf(br.x, bj.x);
    float iy1 = fmaxf(br.y, bj.y);
    float ix2 = fminf(br.z, bj.z);
    float iy2 = fminf(br.w, bj.w);
    float inter = fmaxf(ix2 - ix1, 0.0f) * fmaxf(iy2 - iy1, 0.0f);
    float un = fmaxf((ar + aj) - inter, 1e-9f);
    bool sup = ((inter + inter) - un) > un * 5.9604644775390625e-8f;
    bits |= sup ? (1ull << jj) : 0ull;
  }
  W[((size_t)b * NA + r) * NWORD + kw] = bits;
}

// ---------------------------------------------------------------------------
// K2: decode + register bitonic sort + 4-wave pipelined greedy scan, fused
// per problem. Sorted keys stay in registers; boxes stay in LDS; oL written
// from registers; output gathers from resident obox. W (the only cross-block
// dependency) is produced by wmat_kernel, ordered by the stream.
//   wave 0   : decide chunk c          (rows[c%3], diag[c&1], Korig)
//   wave 1   : commit regs->rows[(c+2)%3], then issue loads of chunk c+3
//   waves 2,3: diag gather chunk c+1 (si halves) -> parity (c+1)&1
// All phases verified: decode+sort (r1-r5), scan v4 (r4-r5), fusion (r3).
// ---------------------------------------------------------------------------
// LDS layout (48912 B):
//  [    0,16384) obox   : decoded boxes, orig order (live whole kernel)
//  [16384,24576) skey   : sort staging (dead after sort)
//  [16384,20480) oL     : sorted->orig map (alias skey; dead at output)
//  [20480,46592) rowsL  : 3 x 64 x 17 u64 (dead at output)
//  [46592,48640) diagLo/diagHi : 2 x (2 x 64 u64) (dead at output)
//  [48640,48768) KorigL
//  [48768,48896) keptS  (live at output)
//  [48896,48900) cntS
//  [16384,36864) outAll : output staging, aliases skey/oL/rowsL head
__global__ __launch_bounds__(256) void sortscan_kernel(
    const float* __restrict__ cls_pred,   // (B, C, A)
    const float* __restrict__ reg_pred,   // (B, 4, A)
    const float* __restrict__ anchors,    // (A, 4)
    const unsigned long long* __restrict__ W,   // (B, NA, NWORD)
    float* __restrict__ out)              // (NP, NA, 5)
{
#pragma clang fp contract(off)
  const int tid = threadIdx.x;
  __shared__ __align__(16) unsigned char smem[48912];
  float4*             obox  = (float4*)(smem);
  unsigned long long* skey  = (unsigned long long*)(smem + 16384);
  int*                oL    = (int*)(smem + 16384);
  unsigned long long* rowsL = (unsigned long long*)(smem + 20480);   // [buf*1088 + row*17 + w]
  unsigned long long* diagLo= (unsigned long long*)(smem + 46592);   // [par*64 + lane]
  unsigned long long* diagHi= (unsigned long long*)(smem + 47616);
  unsigned long long* KorigL= (unsigned long long*)(smem + 48640);
  unsigned long long* keptS = (unsigned long long*)(smem + 48768);
  int*                cntS  = (int*)(smem + 48896);
  float*              outAll= (float*)(smem + 16384);

  const int bc = blockIdx.x;
  const int b  = bc / NCLS;

  if (tid == 0) *cntS = 0;
  __syncthreads();

  // ================= decode + register bitonic sort (verified) ============
  const float* regb = reg_pred + (size_t)b * 4 * NA;
  const float* scb  = cls_pred + (size_t)bc * NA;

  float4 s4 = ((const float4*)scb)[tid];
  float4 x4 = ((const float4*)(regb + 0 * NA))[tid];
  float4 y4 = ((const float4*)(regb + 1 * NA))[tid];
  float4 w4 = ((const float4*)(regb + 2 * NA))[tid];
  float4 h4 = ((const float4*)(regb + 3 * NA))[tid];
  float ss[4]  = {s4.x, s4.y, s4.z, s4.w};
  float dxs[4] = {x4.x, x4.y, x4.z, x4.w};
  float dys[4] = {y4.x, y4.y, y4.z, y4.w};
  float dws[4] = {w4.x, w4.y, w4.z, w4.w};
  float dhs[4] = {h4.x, h4.y, h4.z, h4.w};

  unsigned long long r[4];
  int localcnt = 0;
#pragma unroll
  for (int m = 0; m < 4; ++m) {
    const int a = tid * 4 + m;
    float4 an = ((const float4*)anchors)[a];
    float w  = an.z - an.x;
    float h  = an.w - an.y;
    float cx = an.x + 0.5f * w;
    float cy = an.y + 0.5f * h;
    float dx = dxs[m] * 0.1f;
    float dy = dys[m] * 0.1f;
    float dw = dws[m] * 0.2f;
    float dh = dhs[m] * 0.2f;
    float pcx = cx + dx * w;
    float pcy = cy + dy * h;
    float pw  = expf(dw) * w;
    float ph  = expf(dh) * h;
    float x1 = fmaxf(pcx - 0.5f * pw, 0.0f);
    float y1 = pcy - 0.5f * ph;
    x1 = fmaxf(x1, 0.0f);
    y1 = fmaxf(y1, 0.0f);
    float x2 = fminf(pcx + 0.5f * pw, IMG_W);
    float y2 = fminf(pcy + 0.5f * ph, IMG_H);
    obox[a] = make_float4(x1, y1, x2, y2);

    float s    = ss[m];
    bool valid = (s > 0.05f);
    localcnt  += valid ? 1 : 0;
    float key  = valid ? -s : __int_as_float(0x7f800000);  // +inf if invalid
    r[m] = ((unsigned long long)enc_f32(key) << 32) | (unsigned)a;
  }
  atomicAdd(cntS, localcnt);

  // bitonic network over e = tid*4+m; keys unique (idx in low 32 bits).
#pragma unroll
  for (int kk = 1; kk <= 10; ++kk) {
    const int k = 1 << kk;
#pragma unroll
    for (int jj = kk - 1; jj >= 0; --jj) {
      const int j = 1 << jj;
      if (j >= 256) {
        __syncthreads();
#pragma unroll
        for (int m = 0; m < 4; ++m) skey[tid * 4 + m] = r[m];
        __syncthreads();
#pragma unroll
        for (int m = 0; m < 4; ++m) {
          const int e = tid * 4 + m;
          unsigned long long o = skey[e ^ j];
          const bool up = ((e & k) == 0);
          const bool lo = ((e & j) == 0);
          unsigned long long mn = (r[m] < o) ? r[m] : o;
          unsigned long long mx = (r[m] < o) ? o : r[m];
          r[m] = (lo == up) ? mn : mx;
        }
      } else if (j >= 4) {
        const int d = j >> 2;
        const bool lo = ((tid & d) == 0);
#pragma unroll
        for (int m = 0; m < 4; ++m) {
          const int e = tid * 4 + m;
          const bool up = ((e & k) == 0);
          unsigned long long o = shflx64(r[m], d);
          unsigned long long mn = (r[m] < o) ? r[m] : o;
          unsigned long long mx = (r[m] < o) ? o : r[m];
          r[m] = (lo == up) ? mn : mx;
        }
      } else if (j == 2) {
        const bool up = (((tid * 4) & k) == 0);   // k>=4: uniform over m
        cas64(r[0], r[2], up);
        cas64(r[1], r[3], up);
      } else {  // j == 1
        const bool up01 = (((tid * 4 + 0) & k) == 0);
        const bool up23 = (((tid * 4 + 2) & k) == 0);
        cas64(r[0], r[1], up01);
        cas64(r[2], r[3], up23);
      }
    }
  }

  // ================= 4-wave pipelined scan (verified v4) ==================
  const int lane = tid & 63;
  const int wid  = tid >> 6;     // 0=decide, 1=stage, 2/3=diag halves

  // sorted->orig map from registers (skey dead; oL aliases it)
  __syncthreads();
#pragma unroll
  for (int m = 0; m < 4; ++m) oL[tid * 4 + m] = (int)(unsigned)r[m];
  if (tid < NWORD) { KorigL[tid] = 0ull; keptS[tid] = 0ull; }
  __syncthreads();

  const int nv = *cntS;
  const int nchunk = (nv + 63) >> 6;
  const unsigned long long* Wb = W + (size_t)b * NA * NWORD;

  // ---- prologue: stage rows[0] (waves 0-1) and rows[1] (waves 2-3) ----
  if (nchunk > 0) {
    const int half = wid >> 1;             // 0: rows[0], 1: rows[1]
    const int slot = tid & 127;
    const int rsub8 = slot >> 4;           // 0..7
    const int wsubp = slot & 15;
    if (half == 0 || nchunk > 1) {
      const int cbase = half * 64;
      unsigned long long pre0[8];
#pragma unroll
      for (int t = 0; t < 8; ++t) {
        int orow = oL[cbase + t * 8 + rsub8];
        pre0[t] = Wb[(size_t)orow * NWORD + wsubp];
      }
#pragma unroll
      for (int t = 0; t < 8; ++t)
        rowsL[(size_t)half * 1088 + (t * 8 + rsub8) * 17 + wsubp] = pre0[t];
    }
  }
  __syncthreads();

  const int rsub = lane >> 4;   // stage-wave layout (16 rows x 16 words)
  const int wsub = lane & 15;

  // wave-1 in-flight registers: rows of chunk c+2 at loop-top of iteration c
  unsigned long long pre[16];

  // ---- prologue phase 2: diag[0] (waves 2-3) || wave 1 preloads chunk 2 ----
  if (nchunk > 0 && wid >= 2) {
    const int sbase = (wid - 2) * 32;
    int om = oL[lane];
    int wsel = om >> 6, bsel = om & 63;
    unsigned long long d = 0ull;
#pragma unroll 16
    for (int s = 0; s < 32; ++s) {
      int si = sbase + s;
      d |= ((rowsL[si * 17 + wsel] >> bsel) & 1ull) << si;
    }
    if (wid == 2) diagLo[lane] = d; else diagHi[lane] = d;
  }
  if (wid == 1 && nchunk > 2) {
#pragma unroll
    for (int t = 0; t < 16; ++t) {
      int orow = oL[2 * 64 + t * 4 + rsub];
      pre[t] = Wb[(size_t)orow * NWORD + wsub];
    }
  }
  __syncthreads();

  for (int c = 0; c < nchunk; ++c) {
    if (wid == 1) {
      // commit last iteration's loads (chunk c+2) to rows[(c+2)%3]...
      if (c + 2 < nchunk) {
        const int nb = (c + 2) % 3;
#pragma unroll
        for (int t = 0; t < 16; ++t)
          rowsL[(size_t)nb * 1088 + (t * 4 + rsub) * 17 + wsub] = pre[t];
      }
      // ...then issue loads for chunk c+3 (consumed next iteration)
      if (c + 3 < nchunk) {
#pragma unroll
        for (int t = 0; t < 16; ++t) {
          int orow = oL[(c + 3) * 64 + t * 4 + rsub];
          pre[t] = Wb[(size_t)orow * NWORD + wsub];
        }
      }
    } else if (wid >= 2) {
      // diag for chunk c+1 from rows[(c+1)%3], split si halves
      if (c + 1 < nchunk) {
        const int nb = (c + 1) % 3;
        const int par = (c + 1) & 1;
        const int sbase = (wid - 2) * 32;
        int om = oL[(c + 1) * 64 + lane];
        int wsel = om >> 6, bsel = om & 63;
        unsigned long long d = 0ull;
#pragma unroll 16
        for (int s = 0; s < 32; ++s) {
          int si = sbase + s;
          d |= ((rowsL[(size_t)nb * 1088 + si * 17 + wsel] >> bsel) & 1ull) << si;
        }
        if (wid == 2) diagLo[par * 64 + lane] = d; else diagHi[par * 64 + lane] = d;
      }
    } else {
      // ---- decide chunk c (verified fixed-point loop) ----
      const int cb  = c % 3;
      const int par = c & 1;
      const int sMine = c * 64 + lane;
      const int oMine = oL[sMine];

      unsigned long long pp = 0ull;
      if (c) {
#pragma unroll
        for (int k = 0; k < NWORD; ++k)
          pp |= rowsL[(size_t)cb * 1088 + lane * 17 + k] & KorigL[k];
      }

      unsigned long long diag =
          (diagLo[par * 64 + lane] | diagHi[par * 64 + lane]) & ((1ull << lane) - 1ull);

      unsigned long long valid = __ballot(sMine < nv);
      unsigned long long S     = __ballot(pp != 0ull);
      unsigned long long K  = 0ull;
      unsigned long long Dd = (~valid) | S;
      for (int round = 0; round < 64; ++round) {
        unsigned long long und = ~Dd;
        if (und == 0ull) break;                        // wave-uniform
        bool me_und  = (und >> lane) & 1ull;
        bool blocked = (diag & (K | und)) != 0ull;
        bool isSupp  = (diag & K) != 0ull;
        unsigned long long kb  = __ballot(me_und && !blocked);
        unsigned long long sbm = __ballot(me_und && isSupp);
        K  |= kb;
        Dd |= kb | sbm;
      }
      if (lane == 0) keptS[c] = K;

      if ((K >> lane) & 1ull)
        atomicOr(&KorigL[oMine >> 6], 1ull << (oMine & 63));
    }
    __syncthreads();   // publish rows[c+2], diag[c+1], Korig/kept for c+1
  }

  // ================= output: keys from registers, boxes from LDS ==========
  // outAll aliases now-dead oL/rowsL head; keptS/obox live outside it.
#pragma unroll
  for (int m = 0; m < 4; ++m) {
    const int e = tid * 4 + m;
    unsigned long long kv = r[m];
    int orig = (int)(unsigned)kv;
    bool kp = (keptS[e >> 6] >> (e & 63)) & 1ull;
    float sc = 0.0f;
    float4 ob = make_float4(0.0f, 0.0f, 0.0f, 0.0f);
    if (kp) {
      sc = -__uint_as_float(~(unsigned)(kv >> 32));  // exact original score
      ob = obox[orig];
    }
    float* oa = outAll + (size_t)orig * 5;
    oa[0] = sc; oa[1] = ob.x; oa[2] = ob.y; oa[3] = ob.z; oa[4] = ob.w;
  }
  __syncthreads();

  float4* og = (float4*)(out + (size_t)bc * NA * 5);
  const float4* ol = (const float4*)outAll;
  for (int t4 = tid; t4 < (NA * 5) / 4; t4 += 256) og[t4] = ol[t4];
}

// ---------------------------------------------------------------------------
// Fallback: round-1 monolithic kernel (used only if ws_size is too small)
// ---------------------------------------------------------------------------
__global__ __launch_bounds__(256) void nms_mono_kernel(
    const float* __restrict__ cls_pred,
    const float* __restrict__ reg_pred,
    const float* __restrict__ anchors,
    float* __restrict__ out)
{
#pragma clang fp contract(off)
  const int bc  = blockIdx.x;
  const int b   = bc / NCLS;
  const int tid = threadIdx.x;
  const int BNT = 256, BPT = 4;

  __shared__ __align__(16) unsigned char smem[49152];
  float4*             obox  = (float4*)(smem);
  float4*             sbox  = (float4*)(smem + 16384);
  unsigned long long* skey  = (unsigned long long*)(smem + 32768);
  float*              sarea = (float*)(smem + 40960);
  int*                keepL = (int*)(smem + 45056);

  const float* regb = reg_pred + (size_t)b * 4 * NA;
  const float* scb  = cls_pred + (size_t)bc * NA;
  for (int a = tid; a < NA; a += BNT) {
    float4 an = ((const float4*)anchors)[a];
    float w  = an.z - an.x;
    float h  = an.w - an.y;
    float cx = an.x + 0.5f * w;
    float cy = an.y + 0.5f * h;
    float dx = regb[0 * NA + a] * 0.1f;
    float dy = regb[1 * NA + a] * 0.1f;
    float dw = regb[2 * NA + a] * 0.2f;
    float dh = regb[3 * NA + a] * 0.2f;
    float pcx = cx + dx * w;
    float pcy = cy + dy * h;
    float pw  = expf(dw) * w;
    float ph  = expf(dh) * h;
    float x1 = fmaxf(fmaxf(pcx - 0.5f * pw, 0.0f), 0.0f);
    float y1 = fmaxf(pcy - 0.5f * ph, 0.0f);
    float x2 = fminf(pcx + 0.5f * pw, IMG_W);
    float y2 = fminf(pcy + 0.5f * ph, IMG_H);
    obox[a] = make_float4(x1, y1, x2, y2);
    float s   = scb[a];
    float key = (s > 0.05f) ? -s : __int_as_float(0x7f800000);
    skey[a] = ((unsigned long long)enc_f32(key) << 32) | (unsigned)a;
  }
  __syncthreads();
  for (int k = 2; k <= NA; k <<= 1) {
    for (int j = k >> 1; j > 0; j >>= 1) {
      for (int m = tid; m < NA; m += BNT) {
        int mx = m ^ j;
        if (mx > m) {
          unsigned long long va = skey[m];
          unsigned long long vb = skey[mx];
          bool up = ((m & k) == 0);
          if ((va > vb) == up) { skey[m] = vb; skey[mx] = va; }
        }
      }
      __syncthreads();
    }
  }
  float4 bj[4]; float aj[4]; int kj[4];
#pragma unroll
  for (int m = 0; m < BPT; ++m) {
    int r = tid + m * BNT;
    unsigned long long kv = skey[r];
    int orig = (int)(unsigned)kv;
    float4 bx = obox[orig];
    sbox[r] = bx;
    float ar = (bx.z - bx.x) * (bx.w - bx.y);
    sarea[r] = ar;
    int kp = ((unsigned)(kv >> 32) != 0xFF800000u) ? 1 : 0;
    keepL[r] = kp;
    bj[m] = bx; aj[m] = ar; kj[m] = kp;
  }
  for (int i = 0; i < NA; ++i) {
    __syncthreads();
    if (keepL[i] == 0) continue;
    float4 bi = sbox[i];
    float  ai = sarea[i];
#pragma unroll
    for (int m = 0; m < BPT; ++m) {
      int j = tid + m * BNT;
      if (j > i && kj[m]) {
        float ix1 = fmaxf(bi.x, bj[m].x);
        float iy1 = fmaxf(bi.y, bj[m].y);
        float ix2 = fminf(bi.z, bj[m].z);
        float iy2 = fminf(bi.w, bj[m].w);
        float inter = fmaxf(ix2 - ix1, 0.0f) * fmaxf(iy2 - iy1, 0.0f);
        float un = fmaxf(ai + aj[m] - inter, 1e-9f);
        if (inter / un > 0.5f) { kj[m] = 0; keepL[j] = 0; }
      }
    }
  }
  __syncthreads();
  float4* outbox = obox;
  float*  outsc  = sarea;
#pragma unroll
  for (int m = 0; m < BPT; ++m) {
    int r = tid + m * BNT;
    unsigned long long kv = skey[r];
    int orig = (int)(unsigned)kv;
    float  sc = 0.0f;
    float4 bx = make_float4(0.0f, 0.0f, 0.0f, 0.0f);
    if (kj[m]) {
      sc = -__uint_as_float(~(unsigned)(kv >> 32));
      bx = sbox[r];
    }
    outsc[orig]  = sc;
    outbox[orig] = bx;
  }
  __syncthreads();
  float* ob = out + (size_t)bc * NA * 5;
  for (int a = tid; a < NA; a += BNT) {
    float4 bx = outbox[a];
    float* o = ob + (size_t)a * 5;
    o[0] = outsc[a]; o[1] = bx.x; o[2] = bx.y; o[3] = bx.z; o[4] = bx.w;
  }
}

// ---------------------------------------------------------------------------
extern "C" void kernel_launch(void* const* d_in, const int* in_sizes, int n_in,
                              void* d_out, int out_size, void* d_ws, size_t ws_size,
                              hipStream_t stream) {
  const float* cls = (const float*)d_in[1];
  const float* reg = (const float*)d_in[2];
  const float* anc = (const float*)d_in[3];
  float* out = (float*)d_out;

  // workspace: only the W matrix (256 KB)
  const size_t need = (size_t)BATCH * NA * NWORD * 8;

  if (ws_size < need) {
    nms_mono_kernel<<<dim3(NP), dim3(256), 0, stream>>>(cls, reg, anc, out);
    return;
  }

  unsigned long long* Wm = (unsigned long long*)d_ws;

  wmat_kernel<<<dim3(NWBLK), dim3(256), 0, stream>>>(reg, anc, Wm);
  sortscan_kernel<<<dim3(NP), dim3(256), 0, stream>>>(cls, reg, anc, Wm, out);
}

// Round 7
// 149.583 us; speedup vs baseline: 1.0239x; 1.0239x over previous
//
#include <hip/hip_runtime.h>
#include <stdint.h>

// Problem constants (fixed by setup_inputs): B=2, C=80, A=1024, H=W=2048
#define BATCH 2
#define NCLS 80
#define NP (BATCH * NCLS)   // 160 independent NMS problems
#define NA 1024
#define NWORD 16            // NA/64
#define NWBLK 64            // W-matrix blocks (2 batches x 16 rowblocks x 2 word-halves)
#define IMG_W 2048.0f
#define IMG_H 2048.0f

// monotone float -> uint mapping (ascending uint order == ascending float order)
__device__ __forceinline__ unsigned enc_f32(float f) {
  unsigned u = __float_as_uint(f);
  return (u & 0x80000000u) ? ~u : (u | 0x80000000u);
}

// 64-bit cross-lane xor shuffle (two 32-bit halves; partner always in-wave)
__device__ __forceinline__ unsigned long long shflx64(unsigned long long v, int m) {
  int lo = __shfl_xor((int)(unsigned)v, m, 64);
  int hi = __shfl_xor((int)(unsigned)(v >> 32), m, 64);
  return ((unsigned long long)(unsigned)hi << 32) | (unsigned)lo;
}

__device__ __forceinline__ void cas64(unsigned long long& x, unsigned long long& y, bool up) {
  if ((x > y) == up) { unsigned long long t = x; x = y; y = t; }
}

// ---------------------------------------------------------------------------
// K1 (verified r5): blocks 0..NP-1   = decode + register bitonic sort
//                   blocks NP..NP+63 = per-batch symmetric W matrix
// (sort and W run CONCURRENTLY: 224 blocks <= 256 CUs — r6 showed that
//  serializing W costs ~3 µs; this overlap is the cheap "grid async")
// ---------------------------------------------------------------------------
__global__ __launch_bounds__(256) void prep_kernel(
    const float* __restrict__ cls_pred,   // (B, C, A)
    const float* __restrict__ reg_pred,   // (B, 4, A)
    const float* __restrict__ anchors,    // (A, 4)
    unsigned long long* __restrict__ skeyG,  // (NP, NA)
    float4* __restrict__ sboxG,              // (NP, NA)
    int* __restrict__ nvalidG,               // (NP)
    unsigned long long* __restrict__ W)      // (B, NA, NWORD)
{
#pragma clang fp contract(off)
  const int tid = threadIdx.x;
  __shared__ __align__(16) unsigned char smem[24832];

  if (blockIdx.x < NP) {
    const int bc = blockIdx.x;
    const int b  = bc / NCLS;
    float4*             obox = (float4*)(smem);
    unsigned long long* skey = (unsigned long long*)(smem + 16384);
    int*                cntS = (int*)(smem + 24576);

    if (tid == 0) *cntS = 0;
    __syncthreads();

    const float* regb = reg_pred + (size_t)b * 4 * NA;
    const float* scb  = cls_pred + (size_t)bc * NA;

    // element mapping: e = tid*4 + m -> fully vectorized 16B/lane loads
    float4 s4 = ((const float4*)scb)[tid];
    float4 x4 = ((const float4*)(regb + 0 * NA))[tid];
    float4 y4 = ((const float4*)(regb + 1 * NA))[tid];
    float4 w4 = ((const float4*)(regb + 2 * NA))[tid];
    float4 h4 = ((const float4*)(regb + 3 * NA))[tid];
    float ss[4]  = {s4.x, s4.y, s4.z, s4.w};
    float dxs[4] = {x4.x, x4.y, x4.z, x4.w};
    float dys[4] = {y4.x, y4.y, y4.z, y4.w};
    float dws[4] = {w4.x, w4.y, w4.z, w4.w};
    float dhs[4] = {h4.x, h4.y, h4.z, h4.w};

    unsigned long long r[4];
    int localcnt = 0;
#pragma unroll
    for (int m = 0; m < 4; ++m) {
      const int a = tid * 4 + m;
      float4 an = ((const float4*)anchors)[a];
      float w  = an.z - an.x;
      float h  = an.w - an.y;
      float cx = an.x + 0.5f * w;
      float cy = an.y + 0.5f * h;
      float dx = dxs[m] * 0.1f;
      float dy = dys[m] * 0.1f;
      float dw = dws[m] * 0.2f;
      float dh = dhs[m] * 0.2f;
      float pcx = cx + dx * w;
      float pcy = cy + dy * h;
      float pw  = expf(dw) * w;
      float ph  = expf(dh) * h;
      float x1 = fmaxf(pcx - 0.5f * pw, 0.0f);
      float y1 = pcy - 0.5f * ph;
      x1 = fmaxf(x1, 0.0f);
      y1 = fmaxf(y1, 0.0f);
      float x2 = fminf(pcx + 0.5f * pw, IMG_W);
      float y2 = fminf(pcy + 0.5f * ph, IMG_H);
      obox[a] = make_float4(x1, y1, x2, y2);

      float s    = ss[m];
      bool valid = (s > 0.05f);
      localcnt  += valid ? 1 : 0;
      float key  = valid ? -s : __int_as_float(0x7f800000);  // +inf if invalid
      r[m] = ((unsigned long long)enc_f32(key) << 32) | (unsigned)a;
    }
    atomicAdd(cntS, localcnt);

    // bitonic network over e = tid*4+m; keys unique (idx in low 32 bits).
#pragma unroll
    for (int kk = 1; kk <= 10; ++kk) {
      const int k = 1 << kk;
#pragma unroll
      for (int jj = kk - 1; jj >= 0; --jj) {
        const int j = 1 << jj;
        if (j >= 256) {
          __syncthreads();
#pragma unroll
          for (int m = 0; m < 4; ++m) skey[tid * 4 + m] = r[m];
          __syncthreads();
#pragma unroll
          for (int m = 0; m < 4; ++m) {
            const int e = tid * 4 + m;
            unsigned long long o = skey[e ^ j];
            const bool up = ((e & k) == 0);
            const bool lo = ((e & j) == 0);
            unsigned long long mn = (r[m] < o) ? r[m] : o;
            unsigned long long mx = (r[m] < o) ? o : r[m];
            r[m] = (lo == up) ? mn : mx;
          }
        } else if (j >= 4) {
          const int d = j >> 2;
          const bool lo = ((tid & d) == 0);
#pragma unroll
          for (int m = 0; m < 4; ++m) {
            const int e = tid * 4 + m;
            const bool up = ((e & k) == 0);
            unsigned long long o = shflx64(r[m], d);
            unsigned long long mn = (r[m] < o) ? r[m] : o;
            unsigned long long mx = (r[m] < o) ? o : r[m];
            r[m] = (lo == up) ? mn : mx;
          }
        } else if (j == 2) {
          const bool up = (((tid * 4) & k) == 0);   // k>=4: uniform over m
          cas64(r[0], r[2], up);
          cas64(r[1], r[3], up);
        } else {  // j == 1
          const bool up01 = (((tid * 4 + 0) & k) == 0);
          const bool up23 = (((tid * 4 + 2) & k) == 0);
          cas64(r[0], r[1], up01);
          cas64(r[2], r[3], up23);
        }
      }
    }

    unsigned long long* pk = skeyG + (size_t)bc * NA;
    float4* pb = sboxG + (size_t)bc * NA;
#pragma unroll
    for (int m = 0; m < 4; ++m) {
      unsigned long long kv = r[m];
      pk[tid * 4 + m] = kv;                      // contiguous 32B/lane
      pb[tid * 4 + m] = obox[(int)(unsigned)kv]; // gather + contiguous 64B/lane
    }
    if (tid == 0) nvalidG[bc] = *cntS;

  } else {
    // ================= per-batch symmetric W matrix =================
    const int wb   = blockIdx.x - NP;    // 0..63
    const int b    = wb >> 5;            // batch
    const int sub  = wb & 31;
    const int rblk = sub >> 1;           // 0..15 row block of 64
    const int qh   = sub & 1;            // word half
    const int lane = tid & 63;
    const int wq   = tid >> 6;           // wave id 0..3

    float4* sb = (float4*)(smem);        // 16 KB decoded boxes

    const float* regb = reg_pred + (size_t)b * 4 * NA;
    {
      // vectorized decode, e = tid*4+m (same expressions as before)
      float4 x4 = ((const float4*)(regb + 0 * NA))[tid];
      float4 y4 = ((const float4*)(regb + 1 * NA))[tid];
      float4 w4 = ((const float4*)(regb + 2 * NA))[tid];
      float4 h4 = ((const float4*)(regb + 3 * NA))[tid];
      float dxs[4] = {x4.x, x4.y, x4.z, x4.w};
      float dys[4] = {y4.x, y4.y, y4.z, y4.w};
      float dws[4] = {w4.x, w4.y, w4.z, w4.w};
      float dhs[4] = {h4.x, h4.y, h4.z, h4.w};
#pragma unroll
      for (int m = 0; m < 4; ++m) {
        const int a = tid * 4 + m;
        float4 an = ((const float4*)anchors)[a];
        float w  = an.z - an.x;
        float h  = an.w - an.y;
        float cx = an.x + 0.5f * w;
        float cy = an.y + 0.5f * h;
        float dx = dxs[m] * 0.1f;
        float dy = dys[m] * 0.1f;
        float dw = dws[m] * 0.2f;
        float dh = dhs[m] * 0.2f;
        float pcx = cx + dx * w;
        float pcy = cy + dy * h;
        float pw  = expf(dw) * w;
        float ph  = expf(dh) * h;
        float x1 = fmaxf(pcx - 0.5f * pw, 0.0f);
        float y1 = pcy - 0.5f * ph;
        x1 = fmaxf(x1, 0.0f);
        y1 = fmaxf(y1, 0.0f);
        float x2 = fminf(pcx + 0.5f * pw, IMG_W);
        float y2 = fminf(pcy + 0.5f * ph, IMG_H);
        sb[a] = make_float4(x1, y1, x2, y2);
      }
    }
    __syncthreads();

    const int r = rblk * 64 + lane;      // this lane's row
    float4 br = sb[r];
    float  ar = (br.z - br.x) * (br.w - br.y);
    unsigned long long* wrow = W + ((size_t)b * NA + r) * NWORD;

#pragma unroll
    for (int k2 = 0; k2 < 2; ++k2) {
      const int kw = qh * 8 + wq * 2 + k2;   // word index (wave-uniform)
      const int jbase = kw * 64;
      unsigned long long bits = 0ull;
#pragma unroll 8
      for (int jj = 0; jj < 64; ++jj) {
        float4 bj = sb[jbase + jj];      // wave-broadcast b128
        float  aj = (bj.z - bj.x) * (bj.w - bj.y);
        float ix1 = fmaxf(br.x, bj.x);
        float iy1 = fmaxf(br.y, bj.y);
        float ix2 = fminf(br.z, bj.z);
        float iy2 = fminf(br.w, bj.w);
        float inter = fmaxf(ix2 - ix1, 0.0f) * fmaxf(iy2 - iy1, 0.0f);
        float un = fmaxf((ar + aj) - inter, 1e-9f);
        bool sup = ((inter + inter) - un) > un * 5.9604644775390625e-8f;
        bits |= sup ? (1ull << jj) : 0ull;
      }
      wrow[kw] = bits;
    }
  }
}

// ---------------------------------------------------------------------------
// K2 v5: greedy scan, 4 waves, 3-deep row pipeline + async-STAGE split (T14)
// [verified r5], plus epilogue prefetch: pk is read ONCE in the prologue
// (kept in kv[] registers for the epilogue) and the epilogue's pb boxes are
// issued in the prologue so their latency hides under the 16-chunk loop.
//   wave 0   : decide chunk c          (rows[c%3], diag[c&1], Korig)
//   wave 1   : commit regs->rows[(c+2)%3], then issue loads of chunk c+3
//   waves 2,3: diag gather chunk c+1 (si halves) -> parity (c+1)&1
// ---------------------------------------------------------------------------
__global__ __launch_bounds__(256) void scan_kernel(
    const unsigned long long* __restrict__ skeyG,
    const float4* __restrict__ sboxG,
    const unsigned long long* __restrict__ W,     // (B, NA, NWORD)
    const int* __restrict__ nvalidG,
    float* __restrict__ out)              // (NP, NA, 5)
{
  const int p    = blockIdx.x;
  const int b    = p / NCLS;
  const int tid  = threadIdx.x;
  const int lane = tid & 63;
  const int wid  = tid >> 6;     // 0=decide, 1=stage, 2/3=diag halves

  __shared__ unsigned long long rowsL[3][64 * 17]; // 3 x 8704 B
  __shared__ unsigned long long diagLo[2][64];     // parity x candidate
  __shared__ unsigned long long diagHi[2][64];
  __shared__ int oL[NA];                           // 4 KB sorted->orig map
  __shared__ unsigned long long KorigL[NWORD];
  __shared__ unsigned long long keptS[NWORD];
  __shared__ __align__(16) float outAll[NA * 5];   // 20 KB

  if (tid < NWORD) { KorigL[tid] = 0ull; keptS[tid] = 0ull; }

  const int nv = nvalidG[p];
  const int nchunk = (nv + 63) >> 6;
  const unsigned long long* pk = skeyG + (size_t)p * NA;
  const float4* pb = sboxG + (size_t)p * NA;
  const unsigned long long* Wb = W + (size_t)b * NA * NWORD;

  // prologue: load pk ONCE (kept for epilogue), write oL; issue epilogue's
  // box loads now so their latency spans the whole chunk loop (T14).
  unsigned long long kv[4];
  float4 pbv[4];
#pragma unroll
  for (int t = 0; t < 4; ++t) {
    int r = t * 256 + tid;
    kv[t] = pk[r];
    oL[r] = (int)(unsigned)kv[t];
  }
#pragma unroll
  for (int t = 0; t < 4; ++t) {
    int r = t * 256 + tid;
    pbv[t] = pb[r];
  }
  __syncthreads();

  // ---- prologue: stage rows[0] (waves 0-1) and rows[1] (waves 2-3) ----
  if (nchunk > 0) {
    const int half = wid >> 1;             // 0: rows[0], 1: rows[1]
    const int slot = tid & 127;
    const int rsub8 = slot >> 4;           // 0..7
    const int wsubp = slot & 15;
    if (half == 0 || nchunk > 1) {
      const int cbase = half * 64;
      unsigned long long pre0[8];
#pragma unroll
      for (int t = 0; t < 8; ++t) {
        int orow = oL[cbase + t * 8 + rsub8];
        pre0[t] = Wb[(size_t)orow * NWORD + wsubp];
      }
#pragma unroll
      for (int t = 0; t < 8; ++t)
        rowsL[half][(t * 8 + rsub8) * 17 + wsubp] = pre0[t];
    }
  }
  __syncthreads();

  const int rsub = lane >> 4;   // stage-wave layout (16 rows x 16 words)
  const int wsub = lane & 15;

  // wave-1 in-flight registers: rows of chunk c+2 at loop-top of iteration c
  unsigned long long pre[16];

  // ---- prologue phase 2: diag[0] (waves 2-3) || wave 1 preloads chunk 2 ----
  if (nchunk > 0 && wid >= 2) {
    const int sbase = (wid - 2) * 32;
    int om = oL[lane];
    int wsel = om >> 6, bsel = om & 63;
    unsigned long long d = 0ull;
#pragma unroll 16
    for (int s = 0; s < 32; ++s) {
      int si = sbase + s;
      d |= ((rowsL[0][si * 17 + wsel] >> bsel) & 1ull) << si;
    }
    if (wid == 2) diagLo[0][lane] = d; else diagHi[0][lane] = d;
  }
  if (wid == 1 && nchunk > 2) {
#pragma unroll
    for (int t = 0; t < 16; ++t) {
      int orow = oL[2 * 64 + t * 4 + rsub];
      pre[t] = Wb[(size_t)orow * NWORD + wsub];
    }
  }
  __syncthreads();

  for (int c = 0; c < nchunk; ++c) {
    if (wid == 1) {
      // commit last iteration's loads (chunk c+2) to rows[(c+2)%3]...
      if (c + 2 < nchunk) {
        const int nb = (c + 2) % 3;
#pragma unroll
        for (int t = 0; t < 16; ++t)
          rowsL[nb][(t * 4 + rsub) * 17 + wsub] = pre[t];
      }
      // ...then issue loads for chunk c+3 (consumed next iteration)
      if (c + 3 < nchunk) {
#pragma unroll
        for (int t = 0; t < 16; ++t) {
          int orow = oL[(c + 3) * 64 + t * 4 + rsub];
          pre[t] = Wb[(size_t)orow * NWORD + wsub];
        }
      }
    } else if (wid >= 2) {
      // diag for chunk c+1 from rows[(c+1)%3], split si halves
      if (c + 1 < nchunk) {
        const int nb = (c + 1) % 3;
        const int par = (c + 1) & 1;
        const int sbase = (wid - 2) * 32;
        int om = oL[(c + 1) * 64 + lane];
        int wsel = om >> 6, bsel = om & 63;
        unsigned long long d = 0ull;
#pragma unroll 16
        for (int s = 0; s < 32; ++s) {
          int si = sbase + s;
          d |= ((rowsL[nb][si * 17 + wsel] >> bsel) & 1ull) << si;
        }
        if (wid == 2) diagLo[par][lane] = d; else diagHi[par][lane] = d;
      }
    } else {
      // ---- decide chunk c (verified fixed-point loop) ----
      const int cb  = c % 3;
      const int par = c & 1;
      const int sMine = c * 64 + lane;
      const int oMine = oL[sMine];

      unsigned long long pp = 0ull;
      if (c) {
#pragma unroll
        for (int k = 0; k < NWORD; ++k)
          pp |= rowsL[cb][lane * 17 + k] & KorigL[k];
      }

      unsigned long long diag =
          (diagLo[par][lane] | diagHi[par][lane]) & ((1ull << lane) - 1ull);

      unsigned long long valid = __ballot(sMine < nv);
      unsigned long long S     = __ballot(pp != 0ull);
      unsigned long long K  = 0ull;
      unsigned long long Dd = (~valid) | S;
      for (int round = 0; round < 64; ++round) {
        unsigned long long und = ~Dd;
        if (und == 0ull) break;                        // wave-uniform
        bool me_und  = (und >> lane) & 1ull;
        bool blocked = (diag & (K | und)) != 0ull;
        bool isSupp  = (diag & K) != 0ull;
        unsigned long long kb  = __ballot(me_und && !blocked);
        unsigned long long sbm = __ballot(me_und && isSupp);
        K  |= kb;
        Dd |= kb | sbm;
      }
      if (lane == 0) keptS[c] = K;

      if ((K >> lane) & 1ull)
        atomicOr(&KorigL[oMine >> 6], 1ull << (oMine & 63));
    }
    __syncthreads();   // publish rows[c+2], diag[c+1], Korig/kept for c+1
  }

  // epilogue: keys + boxes already in registers (kv/pbv, loaded prologue)
#pragma unroll
  for (int t = 0; t < 4; ++t) {
    int r = t * 256 + tid;
    int orig = (int)(unsigned)kv[t];
    bool kp = (keptS[r >> 6] >> (r & 63)) & 1ull;
    float sc = 0.0f;
    float4 ob = make_float4(0.0f, 0.0f, 0.0f, 0.0f);
    if (kp) {
      sc = -__uint_as_float(~(unsigned)(kv[t] >> 32));  // exact original score
      ob = pbv[t];
    }
    float* oa = outAll + (size_t)orig * 5;
    oa[0] = sc; oa[1] = ob.x; oa[2] = ob.y; oa[3] = ob.z; oa[4] = ob.w;
  }
  __syncthreads();

  float4* og = (float4*)(out + (size_t)p * NA * 5);
  const float4* ol = (const float4*)outAll;
  for (int t4 = tid; t4 < (NA * 5) / 4; t4 += 256) og[t4] = ol[t4];
}

// ---------------------------------------------------------------------------
// Fallback: round-1 monolithic kernel (used only if ws_size is too small)
// ---------------------------------------------------------------------------
__global__ __launch_bounds__(256) void nms_mono_kernel(
    const float* __restrict__ cls_pred,
    const float* __restrict__ reg_pred,
    const float* __restrict__ anchors,
    float* __restrict__ out)
{
#pragma clang fp contract(off)
  const int bc  = blockIdx.x;
  const int b   = bc / NCLS;
  const int tid = threadIdx.x;
  const int BNT = 256, BPT = 4;

  __shared__ __align__(16) unsigned char smem[49152];
  float4*             obox  = (float4*)(smem);
  float4*             sbox  = (float4*)(smem + 16384);
  unsigned long long* skey  = (unsigned long long*)(smem + 32768);
  float*              sarea = (float*)(smem + 40960);
  int*                keepL = (int*)(smem + 45056);

  const float* regb = reg_pred + (size_t)b * 4 * NA;
  const float* scb  = cls_pred + (size_t)bc * NA;
  for (int a = tid; a < NA; a += BNT) {
    float4 an = ((const float4*)anchors)[a];
    float w  = an.z - an.x;
    float h  = an.w - an.y;
    float cx = an.x + 0.5f * w;
    float cy = an.y + 0.5f * h;
    float dx = regb[0 * NA + a] * 0.1f;
    float dy = regb[1 * NA + a] * 0.1f;
    float dw = regb[2 * NA + a] * 0.2f;
    float dh = regb[3 * NA + a] * 0.2f;
    float pcx = cx + dx * w;
    float pcy = cy + dy * h;
    float pw  = expf(dw) * w;
    float ph  = expf(dh) * h;
    float x1 = fmaxf(fmaxf(pcx - 0.5f * pw, 0.0f), 0.0f);
    float y1 = fmaxf(pcy - 0.5f * ph, 0.0f);
    float x2 = fminf(pcx + 0.5f * pw, IMG_W);
    float y2 = fminf(pcy + 0.5f * ph, IMG_H);
    obox[a] = make_float4(x1, y1, x2, y2);
    float s   = scb[a];
    float key = (s > 0.05f) ? -s : __int_as_float(0x7f800000);
    skey[a] = ((unsigned long long)enc_f32(key) << 32) | (unsigned)a;
  }
  __syncthreads();
  for (int k = 2; k <= NA; k <<= 1) {
    for (int j = k >> 1; j > 0; j >>= 1) {
      for (int m = tid; m < NA; m += BNT) {
        int mx = m ^ j;
        if (mx > m) {
          unsigned long long va = skey[m];
          unsigned long long vb = skey[mx];
          bool up = ((m & k) == 0);
          if ((va > vb) == up) { skey[m] = vb; skey[mx] = va; }
        }
      }
      __syncthreads();
    }
  }
  float4 bj[4]; float aj[4]; int kj[4];
#pragma unroll
  for (int m = 0; m < BPT; ++m) {
    int r = tid + m * BNT;
    unsigned long long kv = skey[r];
    int orig = (int)(unsigned)kv;
    float4 bx = obox[orig];
    sbox[r] = bx;
    float ar = (bx.z - bx.x) * (bx.w - bx.y);
    sarea[r] = ar;
    int kp = ((unsigned)(kv >> 32) != 0xFF800000u) ? 1 : 0;
    keepL[r] = kp;
    bj[m] = bx; aj[m] = ar; kj[m] = kp;
  }
  for (int i = 0; i < NA; ++i) {
    __syncthreads();
    if (keepL[i] == 0) continue;
    float4 bi = sbox[i];
    float  ai = sarea[i];
#pragma unroll
    for (int m = 0; m < BPT; ++m) {
      int j = tid + m * BNT;
      if (j > i && kj[m]) {
        float ix1 = fmaxf(bi.x, bj[m].x);
        float iy1 = fmaxf(bi.y, bj[m].y);
        float ix2 = fminf(bi.z, bj[m].z);
        float iy2 = fminf(bi.w, bj[m].w);
        float inter = fmaxf(ix2 - ix1, 0.0f) * fmaxf(iy2 - iy1, 0.0f);
        float un = fmaxf(ai + aj[m] - inter, 1e-9f);
        if (inter / un > 0.5f) { kj[m] = 0; keepL[j] = 0; }
      }
    }
  }
  __syncthreads();
  float4* outbox = obox;
  float*  outsc  = sarea;
#pragma unroll
  for (int m = 0; m < BPT; ++m) {
    int r = tid + m * BNT;
    unsigned long long kv = skey[r];
    int orig = (int)(unsigned)kv;
    float  sc = 0.0f;
    float4 bx = make_float4(0.0f, 0.0f, 0.0f, 0.0f);
    if (kj[m]) {
      sc = -__uint_as_float(~(unsigned)(kv >> 32));
      bx = sbox[r];
    }
    outsc[orig]  = sc;
    outbox[orig] = bx;
  }
  __syncthreads();
  float* ob = out + (size_t)bc * NA * 5;
  for (int a = tid; a < NA; a += BNT) {
    float4 bx = outbox[a];
    float* o = ob + (size_t)a * 5;
    o[0] = outsc[a]; o[1] = bx.x; o[2] = bx.y; o[3] = bx.z; o[4] = bx.w;
  }
}

// ---------------------------------------------------------------------------
extern "C" void kernel_launch(void* const* d_in, const int* in_sizes, int n_in,
                              void* d_out, int out_size, void* d_ws, size_t ws_size,
                              hipStream_t stream) {
  const float* cls = (const float*)d_in[1];
  const float* reg = (const float*)d_in[2];
  const float* anc = (const float*)d_in[3];
  float* out = (float*)d_out;

  // workspace layout (256B-aligned blocks)
  const size_t off_key = 0;                                    // NP*NA*8
  const size_t off_box = off_key + (size_t)NP * NA * 8;        // NP*NA*16
  const size_t off_w   = off_box + (size_t)NP * NA * 16;       // B*NA*NWORD*8
  const size_t off_nv  = off_w + (size_t)BATCH * NA * NWORD * 8;
  const size_t need    = off_nv + (size_t)NP * sizeof(int);

  if (ws_size < need) {
    nms_mono_kernel<<<dim3(NP), dim3(256), 0, stream>>>(cls, reg, anc, out);
    return;
  }

  char* ws = (char*)d_ws;
  unsigned long long* skeyG = (unsigned long long*)(ws + off_key);
  float4*             sboxG = (float4*)(ws + off_box);
  unsigned long long* Wm    = (unsigned long long*)(ws + off_w);
  int*                nvG   = (int*)(ws + off_nv);

  prep_kernel<<<dim3(NP + NWBLK), dim3(256), 0, stream>>>(
      cls, reg, anc, skeyG, sboxG, nvG, Wm);
  scan_kernel<<<dim3(NP), dim3(256), 0, stream>>>(skeyG, sboxG, Wm, nvG, out);
}